// Round 9
// baseline (953.467 us; speedup 1.0000x reference)
//
#include <hip/hip_runtime.h>
#include <math.h>

#define BB 4
#define SS 2048
#define NH 8
#define HD 64
#define HID 512
#define EPSV 1e-5f

#define NROWS (BB * SS)                // 8192 (b,s) rows
#define QKV_ELEMS (BB * NH * SS * HD)  // 4,194,304
#define TOTROWS (BB * NH * SS)         // 65536 (b,h,s) rows
#define NJT 16                         // j-tiles of 128 in scores

typedef __attribute__((ext_vector_type(8))) short short8;
typedef __attribute__((ext_vector_type(4))) float f32x4;

__device__ __forceinline__ unsigned short f2bf(float f) {
  unsigned u = __builtin_bit_cast(unsigned, f);
  u += 0x7fff + ((u >> 16) & 1);  // RNE
  return (unsigned short)(u >> 16);
}

// |a-b| for 2 packed f16 accumulated into f32 — pinned codegen: exactly
// v_pk_add_f16(neg) + v_and_b32 + v_dot2_f32_f16 (3 instr / 2 elements).
__device__ __forceinline__ float absdiff2(unsigned qa, unsigned kb, float acc,
                                          unsigned ones) {
  unsigned d, ad;
  asm("v_pk_add_f16 %0, %1, %2 neg_lo:[0,1] neg_hi:[0,1]"
      : "=v"(d)
      : "v"(qa), "v"(kb));
  asm("v_and_b32 %0, 0x7fff7fff, %1" : "=v"(ad) : "v"(d));
  asm("v_dot2_f32_f16 %0, %1, %2, %0" : "+v"(acc) : "v"(ad), "v"(ones));
  return acc;
}

// ---------------------------------------------------------------------------
// bf16-MFMA GEMM: C = A(M x 512) @ W(512 x 512)^T + bias.
// 128x128 tile, 256 threads (4 waves, 2x2 quadrants of 64x64), K-step 32.
// ABF16: A is bf16 (ushort) in gmem; else f32 (converted during staging).
// MODE 0: C f32 [m][n].
// MODE 2: C bf16 transposed per head [bh][d][s] (V -> PV B-operand).
// MODE 3: C f16 split-head [bh][s][d] (Q, K for scores).
// ---------------------------------------------------------------------------
template <int MODE, bool ABF16>
__global__ __launch_bounds__(256, 2) void gemm_bf16(const void* __restrict__ Ain,
                                                    const float* __restrict__ W,
                                                    const float* __restrict__ bias,
                                                    void* __restrict__ Cout) {
  __shared__ unsigned short As[128][40];  // 32 k + 8 pad
  __shared__ unsigned short Ws[128][40];
  const int m0 = blockIdx.y * 128;
  const int n0 = blockIdx.x * 128;
  const int tid = threadIdx.x;
  const int lane = tid & 63;
  const int w = tid >> 6;
  const int wr = w >> 1;
  const int wc = w & 1;
  const int l16 = lane & 15;
  const int lq = lane >> 4;

  f32x4 acc[4][4];
#pragma unroll
  for (int mr = 0; mr < 4; ++mr)
#pragma unroll
    for (int nc = 0; nc < 4; ++nc) acc[mr][nc] = (f32x4)0.f;

  for (int k0 = 0; k0 < HID; k0 += 32) {
    __syncthreads();
    if (ABF16) {
      const unsigned short* A = (const unsigned short*)Ain;
#pragma unroll
      for (int p = 0; p < 2; ++p) {
        int idx = tid + p * 256;
        int row = idx >> 2;
        int ch = (idx & 3) * 8;
        *(uint4*)&As[row][ch] = *(const uint4*)&A[(size_t)(m0 + row) * HID + k0 + ch];
      }
#pragma unroll
      for (int p = 0; p < 4; ++p) {
        int idx = tid + p * 256;
        int row = idx >> 3;
        int c4 = (idx & 7) * 4;
        float4 wv = *(const float4*)&W[(size_t)(n0 + row) * HID + k0 + c4];
        ushort4 wb = {f2bf(wv.x), f2bf(wv.y), f2bf(wv.z), f2bf(wv.w)};
        *(ushort4*)&Ws[row][c4] = wb;
      }
    } else {
      const float* A = (const float*)Ain;
#pragma unroll
      for (int p = 0; p < 4; ++p) {
        int idx = tid + p * 256;
        int row = idx >> 3;
        int c4 = (idx & 7) * 4;
        float4 av = *(const float4*)&A[(size_t)(m0 + row) * HID + k0 + c4];
        float4 wv = *(const float4*)&W[(size_t)(n0 + row) * HID + k0 + c4];
        ushort4 ab = {f2bf(av.x), f2bf(av.y), f2bf(av.z), f2bf(av.w)};
        ushort4 wb = {f2bf(wv.x), f2bf(wv.y), f2bf(wv.z), f2bf(wv.w)};
        *(ushort4*)&As[row][c4] = ab;
        *(ushort4*)&Ws[row][c4] = wb;
      }
    }
    __syncthreads();
    const int kb = lq * 8;
    short8 a[4], b[4];
#pragma unroll
    for (int mr = 0; mr < 4; ++mr)
      a[mr] = *(const short8*)&As[wr * 64 + mr * 16 + l16][kb];
#pragma unroll
    for (int nc = 0; nc < 4; ++nc)
      b[nc] = *(const short8*)&Ws[wc * 64 + nc * 16 + l16][kb];
#pragma unroll
    for (int mr = 0; mr < 4; ++mr)
#pragma unroll
      for (int nc = 0; nc < 4; ++nc)
        acc[mr][nc] = __builtin_amdgcn_mfma_f32_16x16x32_bf16(a[mr], b[nc], acc[mr][nc], 0, 0, 0);
  }

#pragma unroll
  for (int nc = 0; nc < 4; ++nc) {
    const int n = n0 + wc * 64 + nc * 16 + l16;
    const float bv = bias[n];
#pragma unroll
    for (int mr = 0; mr < 4; ++mr) {
#pragma unroll
      for (int jj = 0; jj < 4; ++jj) {
        const int m = m0 + wr * 64 + mr * 16 + lq * 4 + jj;
        float v = acc[mr][nc][jj] + bv;
        if (MODE == 0) {
          ((float*)Cout)[(size_t)m * HID + n] = v;
        } else if (MODE == 2) {  // bf16 [bh][d][s]
          const int b_ = m >> 11, s = m & (SS - 1);
          const int h = n >> 6, d = n & 63;
          ((unsigned short*)Cout)[(((size_t)(b_ * NH + h)) * HD + d) * SS + s] = f2bf(v);
        } else {  // MODE 3: f16 [bh][s][d]
          const int b_ = m >> 11, s = m & (SS - 1);
          const int h = n >> 6, d = n & 63;
          _Float16 hv = (_Float16)v;
          ((unsigned short*)Cout)[(((size_t)(b_ * NH + h)) * SS + s) * HD + d] =
              __builtin_bit_cast(unsigned short, hv);
        }
      }
    }
  }
}

// ---------------------------------------------------------------------------
// Scores pass: 64-row i-tile, 128-col j-tiles, 512 threads (8 waves).
// 2x8 micro-tile: thread (trow=tid>>4, cg=tid&15) owns rows {trow, trow+32}
// and cols {cg+16c, c=0..7}. Q for both rows (16 uint4 = 64 VGPR) is hoisted
// OUT of the j-loop — loads cannot sink past __syncthreads, so q re-reads
// are structurally impossible. Recurring LDS = k-reads only (8/chunk),
// the balanced VALU:LDS ideal. __launch_bounds__(512,4): 128-VGPR cap.
// ---------------------------------------------------------------------------
__global__ __launch_bounds__(512, 4) void scores_kernel(
    const unsigned short* __restrict__ Qh, const unsigned short* __restrict__ Kh,
    const int* __restrict__ mask, const float* __restrict__ temp,
    float* __restrict__ attn, float* __restrict__ stats,
    float* __restrict__ msnap) {
  __shared__ unsigned short Qs[64][72];   // 64 f16 + 8 pad (144B rows)
  __shared__ unsigned short Ks[128][72];
  __shared__ int Ms[128];

  const int bh = blockIdx.y;
  const int b = bh >> 3;
  const int h = bh & 7;
  const int i0 = blockIdx.x * 64;
  const int tid = threadIdx.x;
  const int trow = tid >> 4;  // 0..31 -> rows trow, trow+32
  const int cg = tid & 15;    // 0..15 -> cols cg+16c, c=0..7
  const float tmp = temp[h];
  const unsigned ones = 0x3C003C00u;  // packed f16 (1.0, 1.0)

  const unsigned short* Qb = Qh + (size_t)bh * SS * HD;
  const unsigned short* Kb = Kh + (size_t)bh * SS * HD;
  float* attn_b = attn + (size_t)bh * SS * SS;

  // stage Q tile: 64 x 64 f16 = 512 uint4 chunks (1 per thread)
  {
    int row = tid >> 3;
    int ch = (tid & 7) * 8;
    *(uint4*)&Qs[row][ch] = *(const uint4*)&Qb[(size_t)(i0 + row) * HD + ch];
  }
  __syncthreads();

  // hoist q into registers for the whole kernel: 2 rows x 8 chunks = 64 VGPR
  uint4 q0[8], q1[8];
#pragma unroll
  for (int k8 = 0; k8 < 8; ++k8) {
    q0[k8] = *(const uint4*)&Qs[trow][k8 * 8];
    q1[k8] = *(const uint4*)&Qs[trow + 32][k8 * 8];
  }

  float m[2], sg[2];
#pragma unroll
  for (int r = 0; r < 2; ++r) {
    m[r] = -INFINITY;
    sg[r] = 0.f;
  }

  for (int j0 = 0; j0 < SS; j0 += 128) {
    __syncthreads();  // protect Ks reads from previous iteration
// stage K tile: 128 x 64 f16 = 1024 uint4 chunks (2 per thread)
#pragma unroll
    for (int p = 0; p < 2; ++p) {
      int idx = tid + p * 512;
      int row = idx >> 3;
      int ch = (idx & 7) * 8;
      *(uint4*)&Ks[row][ch] = *(const uint4*)&Kb[(size_t)(j0 + row) * HD + ch];
    }
    if (tid < 128) Ms[tid] = mask[b * SS + j0 + tid];
    __syncthreads();

    float d0[8], d1[8];
#pragma unroll
    for (int c = 0; c < 8; ++c) {
      d0[c] = 0.f;
      d1[c] = 0.f;
    }

// k8 unroll 1: only 8 kx loads in flight; q stays in its 64 pinned regs.
#pragma unroll 1
    for (int k8 = 0; k8 < 8; ++k8) {
      const uint4 qa = q0[k8], qb = q1[k8];
#pragma unroll
      for (int c = 0; c < 8; ++c) {
        const uint4 kx = *(const uint4*)&Ks[cg + 16 * c][k8 * 8];
        float a0 = d0[c], a1 = d1[c];
        a0 = absdiff2(qa.x, kx.x, a0, ones);
        a0 = absdiff2(qa.y, kx.y, a0, ones);
        a0 = absdiff2(qa.z, kx.z, a0, ones);
        a0 = absdiff2(qa.w, kx.w, a0, ones);
        a1 = absdiff2(qb.x, kx.x, a1, ones);
        a1 = absdiff2(qb.y, kx.y, a1, ones);
        a1 = absdiff2(qb.z, kx.z, a1, ones);
        a1 = absdiff2(qb.w, kx.w, a1, ones);
        d0[c] = a0;
        d1[c] = a1;
      }
    }

    int msk[8];
#pragma unroll
    for (int c = 0; c < 8; ++c) msk[c] = Ms[cg + 16 * c];

    const int jt = j0 >> 7;
#pragma unroll
    for (int r = 0; r < 2; ++r) {
      float s[8];
      float rmax = -INFINITY;
#pragma unroll
      for (int c = 0; c < 8; ++c) {
        float sc = -(r ? d1[c] : d0[c]) * tmp;
        if (msk[c] == 0) sc = -1e9f;
        s[c] = sc;
        rmax = fmaxf(rmax, sc);
      }
// make row max uniform across the 16 cg lanes
#pragma unroll
      for (int off = 1; off < 16; off <<= 1) rmax = fmaxf(rmax, __shfl_xor(rmax, off));
      const float mnew = fmaxf(m[r], rmax);
      const int i = i0 + trow + 32 * r;
      float* arow = attn_b + (size_t)i * SS + j0;
      float psum = 0.f;
#pragma unroll
      for (int c = 0; c < 8; ++c) {
        float pv = __expf(s[c] - mnew);
        psum += pv;
        arow[cg + 16 * c] = pv;  // store p'
      }
      sg[r] = sg[r] * __expf(m[r] - mnew) + psum;
      m[r] = mnew;
      if (cg == 0) msnap[((size_t)bh * NJT + jt) * SS + i] = mnew;
    }
  }

#pragma unroll
  for (int r = 0; r < 2; ++r) {
    float ssum = sg[r];
#pragma unroll
    for (int off = 1; off < 16; off <<= 1) ssum += __shfl_xor(ssum, off);
    if (cg == 0) {
      const int row = bh * SS + i0 + trow + 32 * r;
      stats[2 * row] = m[r];
      stats[2 * row + 1] = ssum;
    }
  }
}

// ---------------------------------------------------------------------------
// attn_pv: p = p' * exp(msnap - mfin) / sum ; rewrite attn f32 in place;
// PV via bf16 MFMA with pre-transposed V (Vt bf16 [bh][d][s]).
// 64x64 tiles for occupancy (19 KB LDS, grid 1024).
// ---------------------------------------------------------------------------
__global__ __launch_bounds__(256, 4) void attn_pv_kernel(
    const unsigned short* __restrict__ Vt, const float* __restrict__ stats,
    const float* __restrict__ msnap, float* __restrict__ attn,
    unsigned short* __restrict__ attn_out) {
  __shared__ unsigned short Ps[64][72];
  __shared__ unsigned short Vts[64][72];
  __shared__ float corr_s[64];

  const int bh = blockIdx.y;
  const int b = bh >> 3;
  const int h = bh & 7;
  const int i0 = blockIdx.x * 64;
  const int tid = threadIdx.x;
  const int lane = tid & 63;
  const int w = tid >> 6;
  const int wr = w >> 1;
  const int wc = w & 1;
  const int l16 = lane & 15;
  const int lq = lane >> 4;

  float* attn_b = attn + (size_t)bh * SS * SS;
  const unsigned short* Vtb = Vt + (size_t)bh * HD * SS;

  float mfin = 0.f, inv = 0.f;
  if (tid < 64) {
    const int row = bh * SS + i0 + tid;
    mfin = stats[2 * row];
    inv = 1.0f / stats[2 * row + 1];
  }

  f32x4 acc[2][2];
#pragma unroll
  for (int mr = 0; mr < 2; ++mr)
#pragma unroll
    for (int nc = 0; nc < 2; ++nc) acc[mr][nc] = (f32x4)0.f;

  for (int j0 = 0; j0 < SS; j0 += 64) {
    __syncthreads();
    if (tid < 64)
      corr_s[tid] =
          __expf(msnap[((size_t)bh * NJT + (j0 >> 7)) * SS + i0 + tid] - mfin) * inv;
// stage Vt tile: 64 d-rows x 64 j-cols bf16 = 512 uint4 chunks
#pragma unroll
    for (int p = 0; p < 2; ++p) {
      int idx = tid + p * 256;
      int row = idx >> 3;
      int ch = (idx & 7) * 8;
      *(uint4*)&Vts[row][ch] = *(const uint4*)&Vtb[(size_t)row * SS + j0 + ch];
    }
    __syncthreads();
// p-phase: 64x64 f32 RMW = 1024 float4
#pragma unroll
    for (int p = 0; p < 4; ++p) {
      int idx = tid + p * 256;
      int row = idx >> 4;
      int c4 = (idx & 15) * 4;
      float* ap = &attn_b[(size_t)(i0 + row) * SS + j0 + c4];
      float4 pv = *(float4*)ap;
      const float cr = corr_s[row];
      pv.x *= cr;
      pv.y *= cr;
      pv.z *= cr;
      pv.w *= cr;
      *(float4*)ap = pv;
      ushort4 pb = {f2bf(pv.x), f2bf(pv.y), f2bf(pv.z), f2bf(pv.w)};
      *(ushort4*)&Ps[row][c4] = pb;
    }
    __syncthreads();
// MFMA: out(64x64) += P(64x64) @ V(64x64)
#pragma unroll
    for (int ks = 0; ks < 2; ++ks) {
      const int kb = ks * 32 + lq * 8;
      short8 a[2], bf[2];
#pragma unroll
      for (int mr = 0; mr < 2; ++mr)
        a[mr] = *(const short8*)&Ps[wr * 32 + mr * 16 + l16][kb];
#pragma unroll
      for (int nc = 0; nc < 2; ++nc)
        bf[nc] = *(const short8*)&Vts[wc * 32 + nc * 16 + l16][kb];
#pragma unroll
      for (int mr = 0; mr < 2; ++mr)
#pragma unroll
        for (int nc = 0; nc < 2; ++nc)
          acc[mr][nc] = __builtin_amdgcn_mfma_f32_16x16x32_bf16(a[mr], bf[nc], acc[mr][nc], 0, 0, 0);
    }
  }

// epilogue: bf16 write [b, s, h*64 + d]
#pragma unroll
  for (int mr = 0; mr < 2; ++mr)
#pragma unroll
    for (int nc = 0; nc < 2; ++nc)
#pragma unroll
      for (int jj = 0; jj < 4; ++jj) {
        const int i = i0 + wr * 32 + mr * 16 + lq * 4 + jj;
        const int d = wc * 32 + nc * 16 + l16;
        attn_out[((size_t)(b * SS + i)) * HID + h * HD + d] = f2bf(acc[mr][nc][jj]);
      }
}

// ---------------------------------------------------------------------------
// Residual + LayerNorm
// ---------------------------------------------------------------------------
__global__ __launch_bounds__(256) void ln_kernel(const float* __restrict__ proj,
                                                 const float* __restrict__ query,
                                                 const float* __restrict__ gamma,
                                                 const float* __restrict__ beta,
                                                 float* __restrict__ out) {
  const int row = blockIdx.x;
  const int tid = threadIdx.x;

  float x[2];
  float sum = 0.f, sumsq = 0.f;
#pragma unroll
  for (int t = 0; t < 2; ++t) {
    const int c = tid + t * 256;
    float v = proj[(size_t)row * HID + c] + query[(size_t)row * HID + c];
    x[t] = v;
    sum += v;
    sumsq += v * v;
  }
#pragma unroll
  for (int off = 1; off < 64; off <<= 1) {
    sum += __shfl_xor(sum, off);
    sumsq += __shfl_xor(sumsq, off);
  }
  __shared__ float s1[4], s2[4];
  if ((tid & 63) == 0) {
    s1[tid >> 6] = sum;
    s2[tid >> 6] = sumsq;
  }
  __syncthreads();
  sum = s1[0] + s1[1] + s1[2] + s1[3];
  sumsq = s2[0] + s2[1] + s2[2] + s2[3];
  const float mu = sum * (1.f / HID);
  const float var = sumsq * (1.f / HID) - mu * mu;
  const float rstd = rsqrtf(var + EPSV);
#pragma unroll
  for (int t = 0; t < 2; ++t) {
    const int c = tid + t * 256;
    out[(size_t)row * HID + c] = (x[t] - mu) * rstd * gamma[c] + beta[c];
  }
}

// ---------------------------------------------------------------------------
extern "C" void kernel_launch(void* const* d_in, const int* in_sizes, int n_in,
                              void* d_out, int out_size, void* d_ws, size_t ws_size,
                              hipStream_t stream) {
  const float* query = (const float*)d_in[0];
  const float* key = (const float*)d_in[1];
  const float* value = (const float*)d_in[2];
  const int* mask = (const int*)d_in[3];
  const float* Wq = (const float*)d_in[4];
  const float* bq = (const float*)d_in[5];
  const float* Wk = (const float*)d_in[6];
  const float* bk = (const float*)d_in[7];
  const float* Wv = (const float*)d_in[8];
  const float* bv = (const float*)d_in[9];
  const float* Wo = (const float*)d_in[10];
  const float* bo = (const float*)d_in[11];
  const float* temp = (const float*)d_in[12];
  const float* gamma = (const float*)d_in[13];
  const float* beta = (const float*)d_in[14];

  float* out_final = (float*)d_out;                     // (B,S,HID)
  float* attn = (float*)d_out + (size_t)BB * SS * HID;  // (B,H,S,S)

  // workspace layout (36.5 MB total)
  unsigned short* Qh = (unsigned short*)d_ws;    // f16 [bh][s][d]   8MB
  unsigned short* Kh = Qh + QKV_ELEMS;           // f16 [bh][s][d]   8MB
  unsigned short* Vt = Kh + QKV_ELEMS;           // bf16 [bh][d][s]  8MB
  unsigned short* aout = Vt + QKV_ELEMS;         // bf16 [b*s][512]  8MB
  float* stats = (float*)(aout + QKV_ELEMS);     // 2 * TOTROWS      0.5MB
  float* msnap = stats + 2 * TOTROWS;            // NJT * TOTROWS    4MB
  float* proj = (float*)d_ws;                    // f32, aliases Qh+Kh (16MB)

  const dim3 blk(256);
  const dim3 ggrid(HID / 128, NROWS / 128);  // 4 x 64

  gemm_bf16<3, false><<<ggrid, blk, 0, stream>>>(query, Wq, bq, Qh);
  gemm_bf16<3, false><<<ggrid, blk, 0, stream>>>(key, Wk, bk, Kh);
  gemm_bf16<2, false><<<ggrid, blk, 0, stream>>>(value, Wv, bv, Vt);

  const dim3 sgrid(SS / 64, BB * NH);  // 32 x 32
  scores_kernel<<<sgrid, dim3(512), 0, stream>>>(Qh, Kh, mask, temp, attn, stats, msnap);
  attn_pv_kernel<<<sgrid, blk, 0, stream>>>(Vt, stats, msnap, attn, aout);

  gemm_bf16<0, true><<<ggrid, blk, 0, stream>>>(aout, Wo, bo, proj);
  ln_kernel<<<NROWS, blk, 0, stream>>>(proj, query, gamma, beta, out_final);
}

// Round 10
// 899.866 us; speedup vs baseline: 1.0596x; 1.0596x over previous
//
#include <hip/hip_runtime.h>
#include <math.h>

#define BB 4
#define SS 2048
#define NH 8
#define HD 64
#define HID 512
#define EPSV 1e-5f

#define NROWS (BB * SS)                // 8192 (b,s) rows
#define QKV_ELEMS (BB * NH * SS * HD)  // 4,194,304
#define TOTROWS (BB * NH * SS)         // 65536 (b,h,s) rows
#define NJT 16                         // msnap granularity: 128-wide jtiles

typedef __attribute__((ext_vector_type(8))) short short8;
typedef __attribute__((ext_vector_type(4))) float f32x4;

__device__ __forceinline__ unsigned short f2h(float f) {
  _Float16 h = (_Float16)f;
  return __builtin_bit_cast(unsigned short, h);
}
__device__ __forceinline__ float h2f(unsigned short u) {
  return (float)__builtin_bit_cast(_Float16, u);
}

// |a-b| for 2 packed f16 accumulated into f32 — pinned codegen:
// v_pk_add_f16(neg) + v_and_b32 + v_dot2_f32_f16 (3 instr / 2 elements).
__device__ __forceinline__ float absdiff2(unsigned qa, unsigned kb, float acc,
                                          unsigned ones) {
  unsigned d, ad;
  asm("v_pk_add_f16 %0, %1, %2 neg_lo:[0,1] neg_hi:[0,1]"
      : "=v"(d)
      : "v"(qa), "v"(kb));
  asm("v_and_b32 %0, 0x7fff7fff, %1" : "=v"(ad) : "v"(d));
  asm("v_dot2_f32_f16 %0, %1, %2, %0" : "+v"(acc) : "v"(ad), "v"(ones));
  return acc;
}

__device__ __forceinline__ unsigned pk_mul_f16(unsigned a, unsigned b) {
  unsigned r;
  asm("v_pk_mul_f16 %0, %1, %2" : "=v"(r) : "v"(a), "v"(b));
  return r;
}

// ---------------------------------------------------------------------------
// f16-MFMA GEMM: C = A(M x 512) @ W(512 x 512)^T + bias.
// 128x128 tile, 256 threads (4 waves, 2x2 quadrants of 64x64), K-step 32.
// AF16: A is f16 (ushort) in gmem; else f32 (converted during staging).
// MODE 0: C f32 [m][n].
// MODE 2: C f16 transposed per head [bh][d][s] (V -> PV B-operand).
// MODE 3: C f16 split-head [bh][s][d] (Q, K for scores).
// ---------------------------------------------------------------------------
template <int MODE, bool AF16>
__global__ __launch_bounds__(256, 2) void gemm_f16(const void* __restrict__ Ain,
                                                   const float* __restrict__ W,
                                                   const float* __restrict__ bias,
                                                   void* __restrict__ Cout) {
  __shared__ unsigned short As[128][40];  // 32 k + 8 pad
  __shared__ unsigned short Ws[128][40];
  const int m0 = blockIdx.y * 128;
  const int n0 = blockIdx.x * 128;
  const int tid = threadIdx.x;
  const int lane = tid & 63;
  const int w = tid >> 6;
  const int wr = w >> 1;
  const int wc = w & 1;
  const int l16 = lane & 15;
  const int lq = lane >> 4;

  f32x4 acc[4][4];
#pragma unroll
  for (int mr = 0; mr < 4; ++mr)
#pragma unroll
    for (int nc = 0; nc < 4; ++nc) acc[mr][nc] = (f32x4)0.f;

  for (int k0 = 0; k0 < HID; k0 += 32) {
    __syncthreads();
    if (AF16) {
      const unsigned short* A = (const unsigned short*)Ain;
#pragma unroll
      for (int p = 0; p < 2; ++p) {
        int idx = tid + p * 256;
        int row = idx >> 2;
        int ch = (idx & 3) * 8;
        *(uint4*)&As[row][ch] = *(const uint4*)&A[(size_t)(m0 + row) * HID + k0 + ch];
      }
#pragma unroll
      for (int p = 0; p < 4; ++p) {
        int idx = tid + p * 256;
        int row = idx >> 3;
        int c4 = (idx & 7) * 4;
        float4 wv = *(const float4*)&W[(size_t)(n0 + row) * HID + k0 + c4];
        ushort4 wb = {f2h(wv.x), f2h(wv.y), f2h(wv.z), f2h(wv.w)};
        *(ushort4*)&Ws[row][c4] = wb;
      }
    } else {
      const float* A = (const float*)Ain;
#pragma unroll
      for (int p = 0; p < 4; ++p) {
        int idx = tid + p * 256;
        int row = idx >> 3;
        int c4 = (idx & 7) * 4;
        float4 av = *(const float4*)&A[(size_t)(m0 + row) * HID + k0 + c4];
        float4 wv = *(const float4*)&W[(size_t)(n0 + row) * HID + k0 + c4];
        ushort4 ab = {f2h(av.x), f2h(av.y), f2h(av.z), f2h(av.w)};
        ushort4 wb = {f2h(wv.x), f2h(wv.y), f2h(wv.z), f2h(wv.w)};
        *(ushort4*)&As[row][c4] = ab;
        *(ushort4*)&Ws[row][c4] = wb;
      }
    }
    __syncthreads();
    const int kb = lq * 8;
    short8 a[4], b[4];
#pragma unroll
    for (int mr = 0; mr < 4; ++mr)
      a[mr] = *(const short8*)&As[wr * 64 + mr * 16 + l16][kb];
#pragma unroll
    for (int nc = 0; nc < 4; ++nc)
      b[nc] = *(const short8*)&Ws[wc * 64 + nc * 16 + l16][kb];
#pragma unroll
    for (int mr = 0; mr < 4; ++mr)
#pragma unroll
      for (int nc = 0; nc < 4; ++nc)
        acc[mr][nc] = __builtin_amdgcn_mfma_f32_16x16x32_f16(a[mr], b[nc], acc[mr][nc], 0, 0, 0);
  }

#pragma unroll
  for (int nc = 0; nc < 4; ++nc) {
    const int n = n0 + wc * 64 + nc * 16 + l16;
    const float bv = bias[n];
#pragma unroll
    for (int mr = 0; mr < 4; ++mr) {
#pragma unroll
      for (int jj = 0; jj < 4; ++jj) {
        const int m = m0 + wr * 64 + mr * 16 + lq * 4 + jj;
        float v = acc[mr][nc][jj] + bv;
        if (MODE == 0) {
          ((float*)Cout)[(size_t)m * HID + n] = v;
        } else if (MODE == 2) {  // f16 [bh][d][s]
          const int b_ = m >> 11, s = m & (SS - 1);
          const int h = n >> 6, d = n & 63;
          ((unsigned short*)Cout)[(((size_t)(b_ * NH + h)) * HD + d) * SS + s] = f2h(v);
        } else {  // MODE 3: f16 [bh][s][d]
          const int b_ = m >> 11, s = m & (SS - 1);
          const int h = n >> 6, d = n & 63;
          ((unsigned short*)Cout)[(((size_t)(b_ * NH + h)) * SS + s) * HD + d] = f2h(v);
        }
      }
    }
  }
}

// ---------------------------------------------------------------------------
// Scores pass: 64-row i-tile, 128-col j-tiles, 512 threads (8 waves).
// Thread (trow=tid>>4, cg=tid&15) owns rows {i0+trow, i0+trow+32},
// cols {cg+16c, c=0..7}. Q is loaded from GLOBAL into 64 pinned VGPRs with
// fully-static indexing (no LDS remat, no dynamic-index scratch). K staged
// in LDS, read once per (c,k8). Writes p' = exp(s - m_running) as f16 packed
// into the first half of each attn f32 row; msnap + final (m,sum) stats.
// ---------------------------------------------------------------------------
__global__ __launch_bounds__(512, 4) void scores_kernel(
    const unsigned short* __restrict__ Qh, const unsigned short* __restrict__ Kh,
    const int* __restrict__ mask, const float* __restrict__ temp,
    float* __restrict__ attn, float* __restrict__ stats,
    float* __restrict__ msnap) {
  __shared__ unsigned short Ks[128][72];  // 64 f16 + 8 pad (144B rows)
  __shared__ int Ms[128];

  const int bh = blockIdx.y;
  const int b = bh >> 3;
  const int h = bh & 7;
  const int i0 = blockIdx.x * 64;
  const int tid = threadIdx.x;
  const int trow = tid >> 4;  // 0..31
  const int cg = tid & 15;    // 0..15
  const float tmp = temp[h];
  const unsigned ones = 0x3C003C00u;  // packed f16 (1.0, 1.0)

  const unsigned short* Qb = Qh + (size_t)bh * SS * HD;
  const unsigned short* Kb = Kh + (size_t)bh * SS * HD;
  float* attn_b = attn + (size_t)bh * SS * SS;

  const int r0 = i0 + trow;
  const int r1 = r0 + 32;

  // Q rows from global -> registers, fully static (64 VGPRs). L1-resident.
  uint4 q0[8], q1[8];
#pragma unroll
  for (int k8 = 0; k8 < 8; ++k8) {
    q0[k8] = *(const uint4*)&Qb[(size_t)r0 * HD + k8 * 8];
    q1[k8] = *(const uint4*)&Qb[(size_t)r1 * HD + k8 * 8];
  }

  float m0 = -INFINITY, m1 = -INFINITY, sg0 = 0.f, sg1 = 0.f;

  for (int j0 = 0; j0 < SS; j0 += 128) {
    __syncthreads();  // protect Ks reads from previous iteration
// stage K tile: 128 x 64 f16 = 1024 uint4 chunks (2 per thread)
#pragma unroll
    for (int p = 0; p < 2; ++p) {
      int idx = tid + p * 512;
      int row = idx >> 3;
      int ch = (idx & 7) * 8;
      *(uint4*)&Ks[row][ch] = *(const uint4*)&Kb[(size_t)(j0 + row) * HD + ch];
    }
    if (tid < 128) Ms[tid] = mask[b * SS + j0 + tid];
    __syncthreads();

    float d0[8], d1[8];
#pragma unroll
    for (int c = 0; c < 8; ++c) {
      d0[c] = 0.f;
      d1[c] = 0.f;
    }

// fully static unroll: q0/q1 indices are compile-time constants.
#pragma unroll
    for (int k8 = 0; k8 < 8; ++k8) {
      const uint4 qa = q0[k8];
      const uint4 qb = q1[k8];
#pragma unroll
      for (int c = 0; c < 8; ++c) {
        const uint4 kx = *(const uint4*)&Ks[cg + 16 * c][k8 * 8];
        float a0 = d0[c], a1 = d1[c];
        a0 = absdiff2(qa.x, kx.x, a0, ones);
        a0 = absdiff2(qa.y, kx.y, a0, ones);
        a0 = absdiff2(qa.z, kx.z, a0, ones);
        a0 = absdiff2(qa.w, kx.w, a0, ones);
        a1 = absdiff2(qb.x, kx.x, a1, ones);
        a1 = absdiff2(qb.y, kx.y, a1, ones);
        a1 = absdiff2(qb.z, kx.z, a1, ones);
        a1 = absdiff2(qb.w, kx.w, a1, ones);
        d0[c] = a0;
        d1[c] = a1;
      }
    }

    int msk[8];
#pragma unroll
    for (int c = 0; c < 8; ++c) msk[c] = Ms[cg + 16 * c];

    const int jt = j0 >> 7;
    // ---- row 0 ----
    {
      float s[8];
      float rmax = -INFINITY;
#pragma unroll
      for (int c = 0; c < 8; ++c) {
        float sc = -d0[c] * tmp;
        if (msk[c] == 0) sc = -1e9f;
        s[c] = sc;
        rmax = fmaxf(rmax, sc);
      }
#pragma unroll
      for (int off = 1; off < 16; off <<= 1) rmax = fmaxf(rmax, __shfl_xor(rmax, off));
      const float mnew = fmaxf(m0, rmax);
      unsigned short* arow = (unsigned short*)(attn_b + (size_t)r0 * SS);
      float psum = 0.f;
#pragma unroll
      for (int c = 0; c < 8; ++c) {
        float pv = __expf(s[c] - mnew);
        psum += pv;
        arow[j0 + cg + 16 * c] = f2h(pv);  // p' as f16 in row's first half
      }
      sg0 = sg0 * __expf(m0 - mnew) + psum;
      m0 = mnew;
      if (cg == 0) msnap[((size_t)bh * NJT + jt) * SS + r0] = mnew;
    }
    // ---- row 1 ----
    {
      float s[8];
      float rmax = -INFINITY;
#pragma unroll
      for (int c = 0; c < 8; ++c) {
        float sc = -d1[c] * tmp;
        if (msk[c] == 0) sc = -1e9f;
        s[c] = sc;
        rmax = fmaxf(rmax, sc);
      }
#pragma unroll
      for (int off = 1; off < 16; off <<= 1) rmax = fmaxf(rmax, __shfl_xor(rmax, off));
      const float mnew = fmaxf(m1, rmax);
      unsigned short* arow = (unsigned short*)(attn_b + (size_t)r1 * SS);
      float psum = 0.f;
#pragma unroll
      for (int c = 0; c < 8; ++c) {
        float pv = __expf(s[c] - mnew);
        psum += pv;
        arow[j0 + cg + 16 * c] = f2h(pv);
      }
      sg1 = sg1 * __expf(m1 - mnew) + psum;
      m1 = mnew;
      if (cg == 0) msnap[((size_t)bh * NJT + jt) * SS + r1] = mnew;
    }
  }

  {
    float ssum = sg0;
#pragma unroll
    for (int off = 1; off < 16; off <<= 1) ssum += __shfl_xor(ssum, off);
    if (cg == 0) {
      const int row = bh * SS + r0;
      stats[2 * row] = m0;
      stats[2 * row + 1] = ssum;
    }
  }
  {
    float ssum = sg1;
#pragma unroll
    for (int off = 1; off < 16; off <<= 1) ssum += __shfl_xor(ssum, off);
    if (cg == 0) {
      const int row = bh * SS + r1;
      stats[2 * row] = m1;
      stats[2 * row + 1] = ssum;
    }
  }
}

// ---------------------------------------------------------------------------
// K1 attn_pv: read p' f16 from attn rows, p = pk_mul(p', corr_f16),
// PV via f16 MFMA with pre-transposed V (Vt f16 [bh][d][s]) -> aout f16.
// Does NOT write attn (norm_kernel does the f16->f32 expansion).
// ---------------------------------------------------------------------------
__global__ __launch_bounds__(256, 4) void attn_pv_kernel(
    const unsigned short* __restrict__ Vt, const float* __restrict__ stats,
    const float* __restrict__ msnap, const float* __restrict__ attn,
    unsigned short* __restrict__ attn_out) {
  __shared__ unsigned short Ps[64][72];
  __shared__ unsigned short Vts[64][72];
  __shared__ float corr_s[64];

  const int bh = blockIdx.y;
  const int b = bh >> 3;
  const int h = bh & 7;
  const int i0 = blockIdx.x * 64;
  const int tid = threadIdx.x;
  const int lane = tid & 63;
  const int w = tid >> 6;
  const int wr = w >> 1;
  const int wc = w & 1;
  const int l16 = lane & 15;
  const int lq = lane >> 4;

  const float* attn_b = attn + (size_t)bh * SS * SS;
  const unsigned short* Vtb = Vt + (size_t)bh * HD * SS;

  float mfin = 0.f, inv = 0.f;
  if (tid < 64) {
    const int row = bh * SS + i0 + tid;
    mfin = stats[2 * row];
    inv = 1.0f / stats[2 * row + 1];
  }

  f32x4 acc[2][2];
#pragma unroll
  for (int mr = 0; mr < 2; ++mr)
#pragma unroll
    for (int nc = 0; nc < 2; ++nc) acc[mr][nc] = (f32x4)0.f;

  for (int j0 = 0; j0 < SS; j0 += 64) {
    __syncthreads();  // protect prev-iter Ps/Vts reads
    if (tid < 64)
      corr_s[tid] =
          __expf(msnap[((size_t)bh * NJT + (j0 >> 7)) * SS + i0 + tid] - mfin) * inv;
    // stage Vt tile + issue p' loads (independent of corr_s)
    uint4 pv[2];
#pragma unroll
    for (int p = 0; p < 2; ++p) {
      int idx = tid + p * 256;
      int row = idx >> 3;
      int ch = (idx & 7) * 8;
      *(uint4*)&Vts[row][ch] = *(const uint4*)&Vtb[(size_t)row * SS + j0 + ch];
      pv[p] = *(const uint4*)((const unsigned short*)(attn_b + (size_t)(i0 + row) * SS) +
                              j0 + ch);
    }
    __syncthreads();  // corr_s ready
// p = p' * corr (packed f16), stage into Ps
#pragma unroll
    for (int p = 0; p < 2; ++p) {
      int idx = tid + p * 256;
      int row = idx >> 3;
      int ch = (idx & 7) * 8;
      unsigned short cu = f2h(corr_s[row]);
      unsigned c2 = (unsigned)cu | ((unsigned)cu << 16);
      uint4 r;
      r.x = pk_mul_f16(pv[p].x, c2);
      r.y = pk_mul_f16(pv[p].y, c2);
      r.z = pk_mul_f16(pv[p].z, c2);
      r.w = pk_mul_f16(pv[p].w, c2);
      *(uint4*)&Ps[row][ch] = r;
    }
    __syncthreads();
// MFMA: out(64x64) += P(64x64) @ V(64x64)
#pragma unroll
    for (int ks = 0; ks < 2; ++ks) {
      const int kb = ks * 32 + lq * 8;
      short8 a[2], bf[2];
#pragma unroll
      for (int mr = 0; mr < 2; ++mr)
        a[mr] = *(const short8*)&Ps[wr * 32 + mr * 16 + l16][kb];
#pragma unroll
      for (int nc = 0; nc < 2; ++nc)
        bf[nc] = *(const short8*)&Vts[wc * 32 + nc * 16 + l16][kb];
#pragma unroll
      for (int mr = 0; mr < 2; ++mr)
#pragma unroll
        for (int nc = 0; nc < 2; ++nc)
          acc[mr][nc] = __builtin_amdgcn_mfma_f32_16x16x32_f16(a[mr], bf[nc], acc[mr][nc], 0, 0, 0);
    }
  }

// epilogue: f16 write [b, s, h*64 + d]
#pragma unroll
  for (int mr = 0; mr < 2; ++mr)
#pragma unroll
    for (int nc = 0; nc < 2; ++nc)
#pragma unroll
      for (int jj = 0; jj < 4; ++jj) {
        const int i = i0 + wr * 32 + mr * 16 + lq * 4 + jj;
        const int d = wc * 32 + nc * 16 + l16;
        attn_out[((size_t)(b * SS + i)) * HID + h * HD + d] = f2h(acc[mr][nc][jj]);
      }
}

// ---------------------------------------------------------------------------
// K2 normalize: in-place expand each attn row from packed f16 p' (first half
// of the f32 row) to f32 p = p' * corr. One wave per row: all loads complete
// (values consumed) before any store -> no cross-lane hazard. Compiler fence
// prevents TBAA-based reordering of ushort loads vs float stores.
// ---------------------------------------------------------------------------
__global__ __launch_bounds__(256) void norm_kernel(float* __restrict__ attn,
                                                   const float* __restrict__ stats,
                                                   const float* __restrict__ msnap) {
  const int gr = blockIdx.x * 4 + (threadIdx.x >> 6);  // global row 0..65535
  const int lane = threadIdx.x & 63;
  const int bh = gr >> 11;
  const int i = gr & 2047;

  const float mfin = stats[2 * gr];
  const float inv = 1.0f / stats[2 * gr + 1];
  const int jt = lane >> 2;  // (32*lane)>>7, constant per lane
  const float corr = __expf(msnap[((size_t)bh * NJT + jt) * SS + i] - mfin) * inv;

  float* row32 = attn + (size_t)gr * SS;
  const unsigned short* row16 = (const unsigned short*)row32;

  uint4 v[4];
#pragma unroll
  for (int t = 0; t < 4; ++t) v[t] = *(const uint4*)&row16[lane * 32 + t * 8];

  // convert everything first (forces all loads consumed), then fence, store
  float o[32];
#pragma unroll
  for (int t = 0; t < 4; ++t) {
    o[t * 8 + 0] = h2f((unsigned short)(v[t].x)) * corr;
    o[t * 8 + 1] = h2f((unsigned short)(v[t].x >> 16)) * corr;
    o[t * 8 + 2] = h2f((unsigned short)(v[t].y)) * corr;
    o[t * 8 + 3] = h2f((unsigned short)(v[t].y >> 16)) * corr;
    o[t * 8 + 4] = h2f((unsigned short)(v[t].z)) * corr;
    o[t * 8 + 5] = h2f((unsigned short)(v[t].z >> 16)) * corr;
    o[t * 8 + 6] = h2f((unsigned short)(v[t].w)) * corr;
    o[t * 8 + 7] = h2f((unsigned short)(v[t].w >> 16)) * corr;
  }
  asm volatile("" ::: "memory");  // all f16 loads strictly before f32 stores
#pragma unroll
  for (int t = 0; t < 8; ++t) {
    float4 st = {o[t * 4 + 0], o[t * 4 + 1], o[t * 4 + 2], o[t * 4 + 3]};
    *(float4*)&row32[lane * 32 + t * 4] = st;
  }
}

// ---------------------------------------------------------------------------
// Residual + LayerNorm
// ---------------------------------------------------------------------------
__global__ __launch_bounds__(256) void ln_kernel(const float* __restrict__ proj,
                                                 const float* __restrict__ query,
                                                 const float* __restrict__ gamma,
                                                 const float* __restrict__ beta,
                                                 float* __restrict__ out) {
  const int row = blockIdx.x;
  const int tid = threadIdx.x;

  float x[2];
  float sum = 0.f, sumsq = 0.f;
#pragma unroll
  for (int t = 0; t < 2; ++t) {
    const int c = tid + t * 256;
    float v = proj[(size_t)row * HID + c] + query[(size_t)row * HID + c];
    x[t] = v;
    sum += v;
    sumsq += v * v;
  }
#pragma unroll
  for (int off = 1; off < 64; off <<= 1) {
    sum += __shfl_xor(sum, off);
    sumsq += __shfl_xor(sumsq, off);
  }
  __shared__ float s1[4], s2[4];
  if ((tid & 63) == 0) {
    s1[tid >> 6] = sum;
    s2[tid >> 6] = sumsq;
  }
  __syncthreads();
  sum = s1[0] + s1[1] + s1[2] + s1[3];
  sumsq = s2[0] + s2[1] + s2[2] + s2[3];
  const float mu = sum * (1.f / HID);
  const float var = sumsq * (1.f / HID) - mu * mu;
  const float rstd = rsqrtf(var + EPSV);
#pragma unroll
  for (int t = 0; t < 2; ++t) {
    const int c = tid + t * 256;
    out[(size_t)row * HID + c] = (x[t] - mu) * rstd * gamma[c] + beta[c];
  }
}

// ---------------------------------------------------------------------------
extern "C" void kernel_launch(void* const* d_in, const int* in_sizes, int n_in,
                              void* d_out, int out_size, void* d_ws, size_t ws_size,
                              hipStream_t stream) {
  const float* query = (const float*)d_in[0];
  const float* key = (const float*)d_in[1];
  const float* value = (const float*)d_in[2];
  const int* mask = (const int*)d_in[3];
  const float* Wq = (const float*)d_in[4];
  const float* bq = (const float*)d_in[5];
  const float* Wk = (const float*)d_in[6];
  const float* bk = (const float*)d_in[7];
  const float* Wv = (const float*)d_in[8];
  const float* bv = (const float*)d_in[9];
  const float* Wo = (const float*)d_in[10];
  const float* bo = (const float*)d_in[11];
  const float* temp = (const float*)d_in[12];
  const float* gamma = (const float*)d_in[13];
  const float* beta = (const float*)d_in[14];

  float* out_final = (float*)d_out;                     // (B,S,HID)
  float* attn = (float*)d_out + (size_t)BB * SS * HID;  // (B,H,S,S)

  // workspace layout (36.5 MB total)
  unsigned short* Qh = (unsigned short*)d_ws;    // f16 [bh][s][d]   8MB
  unsigned short* Kh = Qh + QKV_ELEMS;           // f16 [bh][s][d]   8MB
  unsigned short* Vt = Kh + QKV_ELEMS;           // f16 [bh][d][s]   8MB
  unsigned short* aout = Vt + QKV_ELEMS;         // f16 [b*s][512]   8MB
  float* stats = (float*)(aout + QKV_ELEMS);     // 2 * TOTROWS      0.5MB
  float* msnap = stats + 2 * TOTROWS;            // NJT * TOTROWS    4MB
  float* proj = (float*)d_ws;                    // f32, aliases Qh+Kh (16MB)

  const dim3 blk(256);
  const dim3 ggrid(HID / 128, NROWS / 128);  // 4 x 64

  gemm_f16<3, false><<<ggrid, blk, 0, stream>>>(query, Wq, bq, Qh);
  gemm_f16<3, false><<<ggrid, blk, 0, stream>>>(key, Wk, bk, Kh);
  gemm_f16<2, false><<<ggrid, blk, 0, stream>>>(value, Wv, bv, Vt);

  const dim3 sgrid(SS / 64, BB * NH);  // 32 x 32
  scores_kernel<<<sgrid, dim3(512), 0, stream>>>(Qh, Kh, mask, temp, attn, stats, msnap);
  attn_pv_kernel<<<sgrid, blk, 0, stream>>>(Vt, stats, msnap, attn, aout);
  norm_kernel<<<TOTROWS / 4, blk, 0, stream>>>(attn, stats, msnap);

  gemm_f16<0, true><<<ggrid, blk, 0, stream>>>(aout, Wo, bo, proj);
  ln_kernel<<<NROWS, blk, 0, stream>>>(proj, query, gamma, beta, out_final);
}

// Round 11
// 848.470 us; speedup vs baseline: 1.1237x; 1.0606x over previous
//
#include <hip/hip_runtime.h>
#include <math.h>

#define BB 4
#define SS 2048
#define NH 8
#define HD 64
#define HID 512
#define EPSV 1e-5f

#define NROWS (BB * SS)                // 8192 (b,s) rows
#define QKV_ELEMS (BB * NH * SS * HD)  // 4,194,304
#define TOTROWS (BB * NH * SS)         // 65536 (b,h,s) rows
#define NJT 16                         // msnap granularity: 128-wide jtiles

typedef __attribute__((ext_vector_type(8))) short short8;
typedef __attribute__((ext_vector_type(4))) float f32x4;

__device__ __forceinline__ unsigned short f2h(float f) {
  _Float16 h = (_Float16)f;
  return __builtin_bit_cast(unsigned short, h);
}
__device__ __forceinline__ float h2f(unsigned short u) {
  return (float)__builtin_bit_cast(_Float16, u);
}

// |a-b| for 2 packed f16 accumulated into f32 — pinned codegen:
// v_pk_add_f16(neg) + v_and_b32 + v_dot2_f32_f16 (3 instr / 2 elements).
__device__ __forceinline__ float absdiff2(unsigned qa, unsigned kb, float acc,
                                          unsigned ones) {
  unsigned d, ad;
  asm("v_pk_add_f16 %0, %1, %2 neg_lo:[0,1] neg_hi:[0,1]"
      : "=v"(d)
      : "v"(qa), "v"(kb));
  asm("v_and_b32 %0, 0x7fff7fff, %1" : "=v"(ad) : "v"(d));
  asm("v_dot2_f32_f16 %0, %1, %2, %0" : "+v"(acc) : "v"(ad), "v"(ones));
  return acc;
}

__device__ __forceinline__ unsigned pk_mul_f16(unsigned a, unsigned b) {
  unsigned r;
  asm("v_pk_mul_f16 %0, %1, %2" : "=v"(r) : "v"(a), "v"(b));
  return r;
}

// ---------------------------------------------------------------------------
// f16-MFMA GEMM: C = A(M x 512) @ W(512 x 512)^T + bias.
// 128x128 tile, 256 threads (4 waves, 2x2 quadrants of 64x64), K-step 32.
// AF16: A is f16 (ushort) in gmem; else f32 (converted during staging).
// MODE 0: C f32 [m][n].
// MODE 2: C f16 transposed per head [bh][d][s] (V -> PV B-operand).
// MODE 3: C f16 split-head [bh][s][d] (Q, K for scores).
// ---------------------------------------------------------------------------
template <int MODE, bool AF16>
__global__ __launch_bounds__(256, 2) void gemm_f16(const void* __restrict__ Ain,
                                                   const float* __restrict__ W,
                                                   const float* __restrict__ bias,
                                                   void* __restrict__ Cout) {
  __shared__ unsigned short As[128][40];  // 32 k + 8 pad
  __shared__ unsigned short Ws[128][40];
  const int m0 = blockIdx.y * 128;
  const int n0 = blockIdx.x * 128;
  const int tid = threadIdx.x;
  const int lane = tid & 63;
  const int w = tid >> 6;
  const int wr = w >> 1;
  const int wc = w & 1;
  const int l16 = lane & 15;
  const int lq = lane >> 4;

  f32x4 acc[4][4];
#pragma unroll
  for (int mr = 0; mr < 4; ++mr)
#pragma unroll
    for (int nc = 0; nc < 4; ++nc) acc[mr][nc] = (f32x4)0.f;

  for (int k0 = 0; k0 < HID; k0 += 32) {
    __syncthreads();
    if (AF16) {
      const unsigned short* A = (const unsigned short*)Ain;
#pragma unroll
      for (int p = 0; p < 2; ++p) {
        int idx = tid + p * 256;
        int row = idx >> 2;
        int ch = (idx & 3) * 8;
        *(uint4*)&As[row][ch] = *(const uint4*)&A[(size_t)(m0 + row) * HID + k0 + ch];
      }
#pragma unroll
      for (int p = 0; p < 4; ++p) {
        int idx = tid + p * 256;
        int row = idx >> 3;
        int c4 = (idx & 7) * 4;
        float4 wv = *(const float4*)&W[(size_t)(n0 + row) * HID + k0 + c4];
        ushort4 wb = {f2h(wv.x), f2h(wv.y), f2h(wv.z), f2h(wv.w)};
        *(ushort4*)&Ws[row][c4] = wb;
      }
    } else {
      const float* A = (const float*)Ain;
#pragma unroll
      for (int p = 0; p < 4; ++p) {
        int idx = tid + p * 256;
        int row = idx >> 3;
        int c4 = (idx & 7) * 4;
        float4 av = *(const float4*)&A[(size_t)(m0 + row) * HID + k0 + c4];
        float4 wv = *(const float4*)&W[(size_t)(n0 + row) * HID + k0 + c4];
        ushort4 ab = {f2h(av.x), f2h(av.y), f2h(av.z), f2h(av.w)};
        ushort4 wb = {f2h(wv.x), f2h(wv.y), f2h(wv.z), f2h(wv.w)};
        *(ushort4*)&As[row][c4] = ab;
        *(ushort4*)&Ws[row][c4] = wb;
      }
    }
    __syncthreads();
    const int kb = lq * 8;
    short8 a[4], b[4];
#pragma unroll
    for (int mr = 0; mr < 4; ++mr)
      a[mr] = *(const short8*)&As[wr * 64 + mr * 16 + l16][kb];
#pragma unroll
    for (int nc = 0; nc < 4; ++nc)
      b[nc] = *(const short8*)&Ws[wc * 64 + nc * 16 + l16][kb];
#pragma unroll
    for (int mr = 0; mr < 4; ++mr)
#pragma unroll
      for (int nc = 0; nc < 4; ++nc)
        acc[mr][nc] = __builtin_amdgcn_mfma_f32_16x16x32_f16(a[mr], b[nc], acc[mr][nc], 0, 0, 0);
  }

#pragma unroll
  for (int nc = 0; nc < 4; ++nc) {
    const int n = n0 + wc * 64 + nc * 16 + l16;
    const float bv = bias[n];
#pragma unroll
    for (int mr = 0; mr < 4; ++mr) {
#pragma unroll
      for (int jj = 0; jj < 4; ++jj) {
        const int m = m0 + wr * 64 + mr * 16 + lq * 4 + jj;
        float v = acc[mr][nc][jj] + bv;
        if (MODE == 0) {
          ((float*)Cout)[(size_t)m * HID + n] = v;
        } else if (MODE == 2) {  // f16 [bh][d][s]
          const int b_ = m >> 11, s = m & (SS - 1);
          const int h = n >> 6, d = n & 63;
          ((unsigned short*)Cout)[(((size_t)(b_ * NH + h)) * HD + d) * SS + s] = f2h(v);
        } else {  // MODE 3: f16 [bh][s][d]
          const int b_ = m >> 11, s = m & (SS - 1);
          const int h = n >> 6, d = n & 63;
          ((unsigned short*)Cout)[(((size_t)(b_ * NH + h)) * SS + s) * HD + d] = f2h(v);
        }
      }
    }
  }
}

// ---------------------------------------------------------------------------
// Scores pass: 64-row i-tile, 128-col j-tiles, 512 threads (8 waves).
// Thread (trow=tid>>4, cg=tid&15) owns rows {i0+trow, i0+trow+32},
// cols {cg+16c, c=0..7}. Q from global into pinned regs (static indexing).
// Writes p' = exp(s - m_running) as f16 into the SECOND HALF of each attn
// f32 row (ushort index 2048+c) so the fused pv_norm kernel can expand
// in place front-to-back without clobbering unread p'.
// ---------------------------------------------------------------------------
__global__ __launch_bounds__(512, 4) void scores_kernel(
    const unsigned short* __restrict__ Qh, const unsigned short* __restrict__ Kh,
    const int* __restrict__ mask, const float* __restrict__ temp,
    float* __restrict__ attn, float* __restrict__ stats,
    float* __restrict__ msnap) {
  __shared__ unsigned short Ks[128][72];  // 64 f16 + 8 pad (144B rows)
  __shared__ int Ms[128];

  const int bh = blockIdx.y;
  const int b = bh >> 3;
  const int h = bh & 7;
  const int i0 = blockIdx.x * 64;
  const int tid = threadIdx.x;
  const int trow = tid >> 4;  // 0..31
  const int cg = tid & 15;    // 0..15
  const float tmp = temp[h];
  const unsigned ones = 0x3C003C00u;  // packed f16 (1.0, 1.0)

  const unsigned short* Qb = Qh + (size_t)bh * SS * HD;
  const unsigned short* Kb = Kh + (size_t)bh * SS * HD;
  float* attn_b = attn + (size_t)bh * SS * SS;

  const int r0 = i0 + trow;
  const int r1 = r0 + 32;

  // Q rows from global -> registers, fully static (64 VGPRs). L1-resident.
  uint4 q0[8], q1[8];
#pragma unroll
  for (int k8 = 0; k8 < 8; ++k8) {
    q0[k8] = *(const uint4*)&Qb[(size_t)r0 * HD + k8 * 8];
    q1[k8] = *(const uint4*)&Qb[(size_t)r1 * HD + k8 * 8];
  }

  float m0 = -INFINITY, m1 = -INFINITY, sg0 = 0.f, sg1 = 0.f;

  for (int j0 = 0; j0 < SS; j0 += 128) {
    __syncthreads();  // protect Ks reads from previous iteration
// stage K tile: 128 x 64 f16 = 1024 uint4 chunks (2 per thread)
#pragma unroll
    for (int p = 0; p < 2; ++p) {
      int idx = tid + p * 512;
      int row = idx >> 3;
      int ch = (idx & 7) * 8;
      *(uint4*)&Ks[row][ch] = *(const uint4*)&Kb[(size_t)(j0 + row) * HD + ch];
    }
    if (tid < 128) Ms[tid] = mask[b * SS + j0 + tid];
    __syncthreads();

    float d0[8], d1[8];
#pragma unroll
    for (int c = 0; c < 8; ++c) {
      d0[c] = 0.f;
      d1[c] = 0.f;
    }

// fully static unroll: q0/q1 indices are compile-time constants.
#pragma unroll
    for (int k8 = 0; k8 < 8; ++k8) {
      const uint4 qa = q0[k8];
      const uint4 qb = q1[k8];
#pragma unroll
      for (int c = 0; c < 8; ++c) {
        const uint4 kx = *(const uint4*)&Ks[cg + 16 * c][k8 * 8];
        float a0 = d0[c], a1 = d1[c];
        a0 = absdiff2(qa.x, kx.x, a0, ones);
        a0 = absdiff2(qa.y, kx.y, a0, ones);
        a0 = absdiff2(qa.z, kx.z, a0, ones);
        a0 = absdiff2(qa.w, kx.w, a0, ones);
        a1 = absdiff2(qb.x, kx.x, a1, ones);
        a1 = absdiff2(qb.y, kx.y, a1, ones);
        a1 = absdiff2(qb.z, kx.z, a1, ones);
        a1 = absdiff2(qb.w, kx.w, a1, ones);
        d0[c] = a0;
        d1[c] = a1;
      }
    }

    int msk[8];
#pragma unroll
    for (int c = 0; c < 8; ++c) msk[c] = Ms[cg + 16 * c];

    const int jt = j0 >> 7;
    // ---- row 0 ----
    {
      float s[8];
      float rmax = -INFINITY;
#pragma unroll
      for (int c = 0; c < 8; ++c) {
        float sc = -d0[c] * tmp;
        if (msk[c] == 0) sc = -1e9f;
        s[c] = sc;
        rmax = fmaxf(rmax, sc);
      }
#pragma unroll
      for (int off = 1; off < 16; off <<= 1) rmax = fmaxf(rmax, __shfl_xor(rmax, off));
      const float mnew = fmaxf(m0, rmax);
      unsigned short* arow = (unsigned short*)(attn_b + (size_t)r0 * SS);
      float psum = 0.f;
#pragma unroll
      for (int c = 0; c < 8; ++c) {
        float pv = __expf(s[c] - mnew);
        psum += pv;
        arow[2048 + j0 + cg + 16 * c] = f2h(pv);  // p' f16, 2nd half of row
      }
      sg0 = sg0 * __expf(m0 - mnew) + psum;
      m0 = mnew;
      if (cg == 0) msnap[((size_t)bh * NJT + jt) * SS + r0] = mnew;
    }
    // ---- row 1 ----
    {
      float s[8];
      float rmax = -INFINITY;
#pragma unroll
      for (int c = 0; c < 8; ++c) {
        float sc = -d1[c] * tmp;
        if (msk[c] == 0) sc = -1e9f;
        s[c] = sc;
        rmax = fmaxf(rmax, sc);
      }
#pragma unroll
      for (int off = 1; off < 16; off <<= 1) rmax = fmaxf(rmax, __shfl_xor(rmax, off));
      const float mnew = fmaxf(m1, rmax);
      unsigned short* arow = (unsigned short*)(attn_b + (size_t)r1 * SS);
      float psum = 0.f;
#pragma unroll
      for (int c = 0; c < 8; ++c) {
        float pv = __expf(s[c] - mnew);
        psum += pv;
        arow[2048 + j0 + cg + 16 * c] = f2h(pv);
      }
      sg1 = sg1 * __expf(m1 - mnew) + psum;
      m1 = mnew;
      if (cg == 0) msnap[((size_t)bh * NJT + jt) * SS + r1] = mnew;
    }
  }

  {
    float ssum = sg0;
#pragma unroll
    for (int off = 1; off < 16; off <<= 1) ssum += __shfl_xor(ssum, off);
    if (cg == 0) {
      const int row = bh * SS + r0;
      stats[2 * row] = m0;
      stats[2 * row + 1] = ssum;
    }
  }
  {
    float ssum = sg1;
#pragma unroll
    for (int off = 1; off < 16; off <<= 1) ssum += __shfl_xor(ssum, off);
    if (cg == 0) {
      const int row = bh * SS + r1;
      stats[2 * row] = m1;
      stats[2 * row + 1] = ssum;
    }
  }
}

// ---------------------------------------------------------------------------
// FUSED pv+norm: per j-tile, read p' f16 (from 2nd half of each attn row),
// p32 = h2f(p') * corr -> write final f32 attn columns in place;
// p16 = pk_mul(p', corr_f16) -> Ps for the PV MFMA -> aout f16.
// Safety: f32 writes for tile j0 (bytes 4*j0..) only ever clobber p' bytes
// (4096+2c) of columns c < j0+64 (already consumed); the single same-tile
// overlap at j0=1984 is fenced by the barrier between p' loads and stores.
// Traffic: 267 MB R + 545 MB W (vs 342 R + 812 W for split pv+norm).
// ---------------------------------------------------------------------------
__global__ __launch_bounds__(256, 4) void attn_pv_norm_kernel(
    const unsigned short* __restrict__ Vt, const float* __restrict__ stats,
    const float* __restrict__ msnap, float* __restrict__ attn,
    unsigned short* __restrict__ attn_out) {
  __shared__ unsigned short Ps[64][72];
  __shared__ unsigned short Vts[64][72];
  __shared__ float corr_s[64];

  const int bh = blockIdx.y;
  const int b = bh >> 3;
  const int h = bh & 7;
  const int i0 = blockIdx.x * 64;
  const int tid = threadIdx.x;
  const int lane = tid & 63;
  const int w = tid >> 6;
  const int wr = w >> 1;
  const int wc = w & 1;
  const int l16 = lane & 15;
  const int lq = lane >> 4;

  float* attn_b = attn + (size_t)bh * SS * SS;
  const unsigned short* Vtb = Vt + (size_t)bh * HD * SS;

  float mfin = 0.f, inv = 0.f;
  if (tid < 64) {
    const int row = bh * SS + i0 + tid;
    mfin = stats[2 * row];
    inv = 1.0f / stats[2 * row + 1];
  }

  f32x4 acc[2][2];
#pragma unroll
  for (int mr = 0; mr < 2; ++mr)
#pragma unroll
    for (int nc = 0; nc < 2; ++nc) acc[mr][nc] = (f32x4)0.f;

  for (int j0 = 0; j0 < SS; j0 += 64) {
    __syncthreads();  // protect prev-iter Ps/Vts reads
    if (tid < 64)
      corr_s[tid] =
          __expf(msnap[((size_t)bh * NJT + (j0 >> 7)) * SS + i0 + tid] - mfin) * inv;
    // stage Vt tile + issue p' loads (p' lives at ushort offset 2048+)
    uint4 pv[2];
#pragma unroll
    for (int p = 0; p < 2; ++p) {
      int idx = tid + p * 256;
      int row = idx >> 3;
      int ch = (idx & 7) * 8;
      *(uint4*)&Vts[row][ch] = *(const uint4*)&Vtb[(size_t)row * SS + j0 + ch];
      pv[p] = *(const uint4*)((const unsigned short*)(attn_b + (size_t)(i0 + row) * SS) +
                              2048 + j0 + ch);
    }
    __syncthreads();  // corr_s ready; all p' loads drained before f32 stores
// p16 = p' * corr (packed f16) -> Ps ; p32 = h2f(p') * corr -> attn f32
#pragma unroll
    for (int p = 0; p < 2; ++p) {
      int idx = tid + p * 256;
      int row = idx >> 3;
      int ch = (idx & 7) * 8;
      const float cr = corr_s[row];
      unsigned short cu = f2h(cr);
      unsigned c2 = (unsigned)cu | ((unsigned)cu << 16);
      uint4 r;
      r.x = pk_mul_f16(pv[p].x, c2);
      r.y = pk_mul_f16(pv[p].y, c2);
      r.z = pk_mul_f16(pv[p].z, c2);
      r.w = pk_mul_f16(pv[p].w, c2);
      *(uint4*)&Ps[row][ch] = r;
      float* orow = attn_b + (size_t)(i0 + row) * SS + j0 + ch;
      float4 o0 = {h2f((unsigned short)(pv[p].x)) * cr,
                   h2f((unsigned short)(pv[p].x >> 16)) * cr,
                   h2f((unsigned short)(pv[p].y)) * cr,
                   h2f((unsigned short)(pv[p].y >> 16)) * cr};
      float4 o1 = {h2f((unsigned short)(pv[p].z)) * cr,
                   h2f((unsigned short)(pv[p].z >> 16)) * cr,
                   h2f((unsigned short)(pv[p].w)) * cr,
                   h2f((unsigned short)(pv[p].w >> 16)) * cr};
      *(float4*)&orow[0] = o0;
      *(float4*)&orow[4] = o1;
    }
    __syncthreads();
// MFMA: out(64x64) += P(64x64) @ V(64x64)
#pragma unroll
    for (int ks = 0; ks < 2; ++ks) {
      const int kb = ks * 32 + lq * 8;
      short8 a[2], bf[2];
#pragma unroll
      for (int mr = 0; mr < 2; ++mr)
        a[mr] = *(const short8*)&Ps[wr * 32 + mr * 16 + l16][kb];
#pragma unroll
      for (int nc = 0; nc < 2; ++nc)
        bf[nc] = *(const short8*)&Vts[wc * 32 + nc * 16 + l16][kb];
#pragma unroll
      for (int mr = 0; mr < 2; ++mr)
#pragma unroll
        for (int nc = 0; nc < 2; ++nc)
          acc[mr][nc] = __builtin_amdgcn_mfma_f32_16x16x32_f16(a[mr], bf[nc], acc[mr][nc], 0, 0, 0);
    }
  }

// epilogue: f16 write [b, s, h*64 + d]
#pragma unroll
  for (int mr = 0; mr < 2; ++mr)
#pragma unroll
    for (int nc = 0; nc < 2; ++nc)
#pragma unroll
      for (int jj = 0; jj < 4; ++jj) {
        const int i = i0 + wr * 32 + mr * 16 + lq * 4 + jj;
        const int d = wc * 32 + nc * 16 + l16;
        attn_out[((size_t)(b * SS + i)) * HID + h * HD + d] = f2h(acc[mr][nc][jj]);
      }
}

// ---------------------------------------------------------------------------
// Residual + LayerNorm
// ---------------------------------------------------------------------------
__global__ __launch_bounds__(256) void ln_kernel(const float* __restrict__ proj,
                                                 const float* __restrict__ query,
                                                 const float* __restrict__ gamma,
                                                 const float* __restrict__ beta,
                                                 float* __restrict__ out) {
  const int row = blockIdx.x;
  const int tid = threadIdx.x;

  float x[2];
  float sum = 0.f, sumsq = 0.f;
#pragma unroll
  for (int t = 0; t < 2; ++t) {
    const int c = tid + t * 256;
    float v = proj[(size_t)row * HID + c] + query[(size_t)row * HID + c];
    x[t] = v;
    sum += v;
    sumsq += v * v;
  }
#pragma unroll
  for (int off = 1; off < 64; off <<= 1) {
    sum += __shfl_xor(sum, off);
    sumsq += __shfl_xor(sumsq, off);
  }
  __shared__ float s1[4], s2[4];
  if ((tid & 63) == 0) {
    s1[tid >> 6] = sum;
    s2[tid >> 6] = sumsq;
  }
  __syncthreads();
  sum = s1[0] + s1[1] + s1[2] + s1[3];
  sumsq = s2[0] + s2[1] + s2[2] + s2[3];
  const float mu = sum * (1.f / HID);
  const float var = sumsq * (1.f / HID) - mu * mu;
  const float rstd = rsqrtf(var + EPSV);
#pragma unroll
  for (int t = 0; t < 2; ++t) {
    const int c = tid + t * 256;
    out[(size_t)row * HID + c] = (x[t] - mu) * rstd * gamma[c] + beta[c];
  }
}

// ---------------------------------------------------------------------------
extern "C" void kernel_launch(void* const* d_in, const int* in_sizes, int n_in,
                              void* d_out, int out_size, void* d_ws, size_t ws_size,
                              hipStream_t stream) {
  const float* query = (const float*)d_in[0];
  const float* key = (const float*)d_in[1];
  const float* value = (const float*)d_in[2];
  const int* mask = (const int*)d_in[3];
  const float* Wq = (const float*)d_in[4];
  const float* bq = (const float*)d_in[5];
  const float* Wk = (const float*)d_in[6];
  const float* bk = (const float*)d_in[7];
  const float* Wv = (const float*)d_in[8];
  const float* bv = (const float*)d_in[9];
  const float* Wo = (const float*)d_in[10];
  const float* bo = (const float*)d_in[11];
  const float* temp = (const float*)d_in[12];
  const float* gamma = (const float*)d_in[13];
  const float* beta = (const float*)d_in[14];

  float* out_final = (float*)d_out;                     // (B,S,HID)
  float* attn = (float*)d_out + (size_t)BB * SS * HID;  // (B,H,S,S)

  // workspace layout (36.5 MB total)
  unsigned short* Qh = (unsigned short*)d_ws;    // f16 [bh][s][d]   8MB
  unsigned short* Kh = Qh + QKV_ELEMS;           // f16 [bh][s][d]   8MB
  unsigned short* Vt = Kh + QKV_ELEMS;           // f16 [bh][d][s]   8MB
  unsigned short* aout = Vt + QKV_ELEMS;         // f16 [b*s][512]   8MB
  float* stats = (float*)(aout + QKV_ELEMS);     // 2 * TOTROWS      0.5MB
  float* msnap = stats + 2 * TOTROWS;            // NJT * TOTROWS    4MB
  float* proj = (float*)d_ws;                    // f32, aliases Qh+Kh (16MB)

  const dim3 blk(256);
  const dim3 ggrid(HID / 128, NROWS / 128);  // 4 x 64

  gemm_f16<3, false><<<ggrid, blk, 0, stream>>>(query, Wq, bq, Qh);
  gemm_f16<3, false><<<ggrid, blk, 0, stream>>>(key, Wk, bk, Kh);
  gemm_f16<2, false><<<ggrid, blk, 0, stream>>>(value, Wv, bv, Vt);

  const dim3 sgrid(SS / 64, BB * NH);  // 32 x 32
  scores_kernel<<<sgrid, dim3(512), 0, stream>>>(Qh, Kh, mask, temp, attn, stats, msnap);
  attn_pv_norm_kernel<<<sgrid, blk, 0, stream>>>(Vt, stats, msnap, attn, aout);

  gemm_f16<0, true><<<ggrid, blk, 0, stream>>>(aout, Wo, bo, proj);
  ln_kernel<<<NROWS, blk, 0, stream>>>(proj, query, gamma, beta, out_final);
}

// Round 12
// 647.264 us; speedup vs baseline: 1.4731x; 1.3109x over previous
//
#include <hip/hip_runtime.h>
#include <math.h>

#define BB 4
#define SS 2048
#define NH 8
#define HD 64
#define HID 512
#define EPSV 1e-5f

#define NROWS (BB * SS)                // 8192 (b,s) rows
#define QKV_ELEMS (BB * NH * SS * HD)  // 4,194,304
#define TOTROWS (BB * NH * SS)         // 65536 (b,h,s) rows
#define NJT 16                         // msnap granularity: 128-wide jtiles

typedef __attribute__((ext_vector_type(8))) short short8;
typedef __attribute__((ext_vector_type(4))) float f32x4;

__device__ __forceinline__ unsigned short f2h(float f) {
  _Float16 h = (_Float16)f;
  return __builtin_bit_cast(unsigned short, h);
}
__device__ __forceinline__ float h2f(unsigned short u) {
  return (float)__builtin_bit_cast(_Float16, u);
}

// SAD of 2 packed u16 with accumulate: acc += |a.h0-b.h0| + |a.h1-b.h1|.
// Q/K are u16 fixed-point: u = round((x+8)*4096); offsets cancel in the
// subtraction so acc = 4096 * sum|q-k| exactly.
__device__ __forceinline__ void sad2(unsigned qa, unsigned kb, unsigned& acc) {
  asm("v_sad_u16 %0, %1, %2, %0" : "+v"(acc) : "v"(qa), "v"(kb));
}

__device__ __forceinline__ unsigned pk_mul_f16(unsigned a, unsigned b) {
  unsigned r;
  asm("v_pk_mul_f16 %0, %1, %2" : "=v"(r) : "v"(a), "v"(b));
  return r;
}

// ---------------------------------------------------------------------------
// f16-MFMA GEMM: C = A(M x 512) @ W(512 x 512)^T + bias.
// 128x128 tile, 256 threads (4 waves, 2x2 quadrants of 64x64), K-step 32.
// AF16: A is f16 (ushort) in gmem; else f32 (converted during staging).
// MODE 0: C f32 [m][n].
// MODE 2: C f16 transposed per head [bh][d][s] (V -> PV B-operand).
// MODE 3: C u16 FIXED-POINT split-head [bh][s][d] (Q, K for SAD scores):
//         u = clamp(round((v + 8) * 4096), 0, 65535).
// ---------------------------------------------------------------------------
template <int MODE, bool AF16>
__global__ __launch_bounds__(256, 2) void gemm_f16(const void* __restrict__ Ain,
                                                   const float* __restrict__ W,
                                                   const float* __restrict__ bias,
                                                   void* __restrict__ Cout) {
  __shared__ unsigned short As[128][40];  // 32 k + 8 pad
  __shared__ unsigned short Ws[128][40];
  const int m0 = blockIdx.y * 128;
  const int n0 = blockIdx.x * 128;
  const int tid = threadIdx.x;
  const int lane = tid & 63;
  const int w = tid >> 6;
  const int wr = w >> 1;
  const int wc = w & 1;
  const int l16 = lane & 15;
  const int lq = lane >> 4;

  f32x4 acc[4][4];
#pragma unroll
  for (int mr = 0; mr < 4; ++mr)
#pragma unroll
    for (int nc = 0; nc < 4; ++nc) acc[mr][nc] = (f32x4)0.f;

  for (int k0 = 0; k0 < HID; k0 += 32) {
    __syncthreads();
    if (AF16) {
      const unsigned short* A = (const unsigned short*)Ain;
#pragma unroll
      for (int p = 0; p < 2; ++p) {
        int idx = tid + p * 256;
        int row = idx >> 2;
        int ch = (idx & 3) * 8;
        *(uint4*)&As[row][ch] = *(const uint4*)&A[(size_t)(m0 + row) * HID + k0 + ch];
      }
#pragma unroll
      for (int p = 0; p < 4; ++p) {
        int idx = tid + p * 256;
        int row = idx >> 3;
        int c4 = (idx & 7) * 4;
        float4 wv = *(const float4*)&W[(size_t)(n0 + row) * HID + k0 + c4];
        ushort4 wb = {f2h(wv.x), f2h(wv.y), f2h(wv.z), f2h(wv.w)};
        *(ushort4*)&Ws[row][c4] = wb;
      }
    } else {
      const float* A = (const float*)Ain;
#pragma unroll
      for (int p = 0; p < 4; ++p) {
        int idx = tid + p * 256;
        int row = idx >> 3;
        int c4 = (idx & 7) * 4;
        float4 av = *(const float4*)&A[(size_t)(m0 + row) * HID + k0 + c4];
        float4 wv = *(const float4*)&W[(size_t)(n0 + row) * HID + k0 + c4];
        ushort4 ab = {f2h(av.x), f2h(av.y), f2h(av.z), f2h(av.w)};
        ushort4 wb = {f2h(wv.x), f2h(wv.y), f2h(wv.z), f2h(wv.w)};
        *(ushort4*)&As[row][c4] = ab;
        *(ushort4*)&Ws[row][c4] = wb;
      }
    }
    __syncthreads();
    const int kb = lq * 8;
    short8 a[4], b[4];
#pragma unroll
    for (int mr = 0; mr < 4; ++mr)
      a[mr] = *(const short8*)&As[wr * 64 + mr * 16 + l16][kb];
#pragma unroll
    for (int nc = 0; nc < 4; ++nc)
      b[nc] = *(const short8*)&Ws[wc * 64 + nc * 16 + l16][kb];
#pragma unroll
    for (int mr = 0; mr < 4; ++mr)
#pragma unroll
      for (int nc = 0; nc < 4; ++nc)
        acc[mr][nc] = __builtin_amdgcn_mfma_f32_16x16x32_f16(a[mr], b[nc], acc[mr][nc], 0, 0, 0);
  }

#pragma unroll
  for (int nc = 0; nc < 4; ++nc) {
    const int n = n0 + wc * 64 + nc * 16 + l16;
    const float bv = bias[n];
#pragma unroll
    for (int mr = 0; mr < 4; ++mr) {
#pragma unroll
      for (int jj = 0; jj < 4; ++jj) {
        const int m = m0 + wr * 64 + mr * 16 + lq * 4 + jj;
        float v = acc[mr][nc][jj] + bv;
        if (MODE == 0) {
          ((float*)Cout)[(size_t)m * HID + n] = v;
        } else if (MODE == 2) {  // f16 [bh][d][s]
          const int b_ = m >> 11, s = m & (SS - 1);
          const int h = n >> 6, d = n & 63;
          ((unsigned short*)Cout)[(((size_t)(b_ * NH + h)) * HD + d) * SS + s] = f2h(v);
        } else {  // MODE 3: u16 fixed-point [bh][s][d]
          const int b_ = m >> 11, s = m & (SS - 1);
          const int h = n >> 6, d = n & 63;
          int u = (int)floorf(fmaf(v, 4096.f, 32768.5f));
          u = u < 0 ? 0 : (u > 65535 ? 65535 : u);
          ((unsigned short*)Cout)[(((size_t)(b_ * NH + h)) * SS + s) * HD + d] =
              (unsigned short)u;
        }
      }
    }
  }
}

// ---------------------------------------------------------------------------
// Scores pass: 64-row i-tile, 128-col j-tiles, 512 threads (8 waves).
// Thread (trow=tid>>4, cg=tid&15) owns rows {i0+trow, i0+trow+32},
// cols {cg+16c, c=0..7}. Q/K are u16 fixed-point; dist via v_sad_u16
// (1 instr / 2 elems, built-in accumulate). Q from global into pinned regs.
// Writes p' = exp(s - m_running) f16 into the SECOND HALF of each attn row.
// ---------------------------------------------------------------------------
__global__ __launch_bounds__(512, 4) void scores_kernel(
    const unsigned short* __restrict__ Qh, const unsigned short* __restrict__ Kh,
    const int* __restrict__ mask, const float* __restrict__ temp,
    float* __restrict__ attn, float* __restrict__ stats,
    float* __restrict__ msnap) {
  __shared__ unsigned short Ks[128][72];  // 64 u16 + 8 pad (144B rows)
  __shared__ int Ms[128];

  const int bh = blockIdx.y;
  const int b = bh >> 3;
  const int h = bh & 7;
  const int i0 = blockIdx.x * 64;
  const int tid = threadIdx.x;
  const int trow = tid >> 4;  // 0..31
  const int cg = tid & 15;    // 0..15
  const float tscale = temp[h] * (1.0f / 4096.0f);  // dist = sad * 2^-12

  const unsigned short* Qb = Qh + (size_t)bh * SS * HD;
  const unsigned short* Kb = Kh + (size_t)bh * SS * HD;
  float* attn_b = attn + (size_t)bh * SS * SS;

  const int r0 = i0 + trow;
  const int r1 = r0 + 32;

  // Q rows from global -> registers, fully static (64 VGPRs). L1-resident.
  uint4 q0[8], q1[8];
#pragma unroll
  for (int k8 = 0; k8 < 8; ++k8) {
    q0[k8] = *(const uint4*)&Qb[(size_t)r0 * HD + k8 * 8];
    q1[k8] = *(const uint4*)&Qb[(size_t)r1 * HD + k8 * 8];
  }

  float m0 = -INFINITY, m1 = -INFINITY, sg0 = 0.f, sg1 = 0.f;

  for (int j0 = 0; j0 < SS; j0 += 128) {
    __syncthreads();  // protect Ks reads from previous iteration
// stage K tile: 128 x 64 u16 = 1024 uint4 chunks (2 per thread)
#pragma unroll
    for (int p = 0; p < 2; ++p) {
      int idx = tid + p * 512;
      int row = idx >> 3;
      int ch = (idx & 7) * 8;
      *(uint4*)&Ks[row][ch] = *(const uint4*)&Kb[(size_t)(j0 + row) * HD + ch];
    }
    if (tid < 128) Ms[tid] = mask[b * SS + j0 + tid];
    __syncthreads();

    unsigned d0[8], d1[8];
#pragma unroll
    for (int c = 0; c < 8; ++c) {
      d0[c] = 0u;
      d1[c] = 0u;
    }

// fully static unroll: q0/q1 indices are compile-time constants.
// 1 v_sad_u16 per dword pair: 8 per (k8,c) for 2 rows.
#pragma unroll
    for (int k8 = 0; k8 < 8; ++k8) {
      const uint4 qa = q0[k8];
      const uint4 qb = q1[k8];
#pragma unroll
      for (int c = 0; c < 8; ++c) {
        const uint4 kx = *(const uint4*)&Ks[cg + 16 * c][k8 * 8];
        sad2(qa.x, kx.x, d0[c]);
        sad2(qa.y, kx.y, d0[c]);
        sad2(qa.z, kx.z, d0[c]);
        sad2(qa.w, kx.w, d0[c]);
        sad2(qb.x, kx.x, d1[c]);
        sad2(qb.y, kx.y, d1[c]);
        sad2(qb.z, kx.z, d1[c]);
        sad2(qb.w, kx.w, d1[c]);
      }
    }

    int msk[8];
#pragma unroll
    for (int c = 0; c < 8; ++c) msk[c] = Ms[cg + 16 * c];

    const int jt = j0 >> 7;
    // ---- row 0 ----
    {
      float s[8];
      float rmax = -INFINITY;
#pragma unroll
      for (int c = 0; c < 8; ++c) {
        float sc = -(float)d0[c] * tscale;
        if (msk[c] == 0) sc = -1e9f;
        s[c] = sc;
        rmax = fmaxf(rmax, sc);
      }
#pragma unroll
      for (int off = 1; off < 16; off <<= 1) rmax = fmaxf(rmax, __shfl_xor(rmax, off));
      const float mnew = fmaxf(m0, rmax);
      unsigned short* arow = (unsigned short*)(attn_b + (size_t)r0 * SS);
      float psum = 0.f;
#pragma unroll
      for (int c = 0; c < 8; ++c) {
        float pv = __expf(s[c] - mnew);
        psum += pv;
        arow[2048 + j0 + cg + 16 * c] = f2h(pv);  // p' f16, 2nd half of row
      }
      sg0 = sg0 * __expf(m0 - mnew) + psum;
      m0 = mnew;
      if (cg == 0) msnap[((size_t)bh * NJT + jt) * SS + r0] = mnew;
    }
    // ---- row 1 ----
    {
      float s[8];
      float rmax = -INFINITY;
#pragma unroll
      for (int c = 0; c < 8; ++c) {
        float sc = -(float)d1[c] * tscale;
        if (msk[c] == 0) sc = -1e9f;
        s[c] = sc;
        rmax = fmaxf(rmax, sc);
      }
#pragma unroll
      for (int off = 1; off < 16; off <<= 1) rmax = fmaxf(rmax, __shfl_xor(rmax, off));
      const float mnew = fmaxf(m1, rmax);
      unsigned short* arow = (unsigned short*)(attn_b + (size_t)r1 * SS);
      float psum = 0.f;
#pragma unroll
      for (int c = 0; c < 8; ++c) {
        float pv = __expf(s[c] - mnew);
        psum += pv;
        arow[2048 + j0 + cg + 16 * c] = f2h(pv);
      }
      sg1 = sg1 * __expf(m1 - mnew) + psum;
      m1 = mnew;
      if (cg == 0) msnap[((size_t)bh * NJT + jt) * SS + r1] = mnew;
    }
  }

  {
    float ssum = sg0;
#pragma unroll
    for (int off = 1; off < 16; off <<= 1) ssum += __shfl_xor(ssum, off);
    if (cg == 0) {
      const int row = bh * SS + r0;
      stats[2 * row] = m0;
      stats[2 * row + 1] = ssum;
    }
  }
  {
    float ssum = sg1;
#pragma unroll
    for (int off = 1; off < 16; off <<= 1) ssum += __shfl_xor(ssum, off);
    if (cg == 0) {
      const int row = bh * SS + r1;
      stats[2 * row] = m1;
      stats[2 * row + 1] = ssum;
    }
  }
}

// ---------------------------------------------------------------------------
// FUSED pv+norm: per j-tile, read p' f16 (from 2nd half of each attn row),
// p32 = h2f(p') * corr -> write final f32 attn columns in place;
// p16 = pk_mul(p', corr_f16) -> Ps for the PV MFMA -> aout f16.
// ---------------------------------------------------------------------------
__global__ __launch_bounds__(256, 4) void attn_pv_norm_kernel(
    const unsigned short* __restrict__ Vt, const float* __restrict__ stats,
    const float* __restrict__ msnap, float* __restrict__ attn,
    unsigned short* __restrict__ attn_out) {
  __shared__ unsigned short Ps[64][72];
  __shared__ unsigned short Vts[64][72];
  __shared__ float corr_s[64];

  const int bh = blockIdx.y;
  const int b = bh >> 3;
  const int h = bh & 7;
  const int i0 = blockIdx.x * 64;
  const int tid = threadIdx.x;
  const int lane = tid & 63;
  const int w = tid >> 6;
  const int wr = w >> 1;
  const int wc = w & 1;
  const int l16 = lane & 15;
  const int lq = lane >> 4;

  float* attn_b = attn + (size_t)bh * SS * SS;
  const unsigned short* Vtb = Vt + (size_t)bh * HD * SS;

  float mfin = 0.f, inv = 0.f;
  if (tid < 64) {
    const int row = bh * SS + i0 + tid;
    mfin = stats[2 * row];
    inv = 1.0f / stats[2 * row + 1];
  }

  f32x4 acc[2][2];
#pragma unroll
  for (int mr = 0; mr < 2; ++mr)
#pragma unroll
    for (int nc = 0; nc < 2; ++nc) acc[mr][nc] = (f32x4)0.f;

  for (int j0 = 0; j0 < SS; j0 += 64) {
    __syncthreads();  // protect prev-iter Ps/Vts reads
    if (tid < 64)
      corr_s[tid] =
          __expf(msnap[((size_t)bh * NJT + (j0 >> 7)) * SS + i0 + tid] - mfin) * inv;
    // stage Vt tile + issue p' loads (p' lives at ushort offset 2048+)
    uint4 pv[2];
#pragma unroll
    for (int p = 0; p < 2; ++p) {
      int idx = tid + p * 256;
      int row = idx >> 3;
      int ch = (idx & 7) * 8;
      *(uint4*)&Vts[row][ch] = *(const uint4*)&Vtb[(size_t)row * SS + j0 + ch];
      pv[p] = *(const uint4*)((const unsigned short*)(attn_b + (size_t)(i0 + row) * SS) +
                              2048 + j0 + ch);
    }
    __syncthreads();  // corr_s ready; all p' loads drained before f32 stores
// p16 = p' * corr (packed f16) -> Ps ; p32 = h2f(p') * corr -> attn f32
#pragma unroll
    for (int p = 0; p < 2; ++p) {
      int idx = tid + p * 256;
      int row = idx >> 3;
      int ch = (idx & 7) * 8;
      const float cr = corr_s[row];
      unsigned short cu = f2h(cr);
      unsigned c2 = (unsigned)cu | ((unsigned)cu << 16);
      uint4 r;
      r.x = pk_mul_f16(pv[p].x, c2);
      r.y = pk_mul_f16(pv[p].y, c2);
      r.z = pk_mul_f16(pv[p].z, c2);
      r.w = pk_mul_f16(pv[p].w, c2);
      *(uint4*)&Ps[row][ch] = r;
      float* orow = attn_b + (size_t)(i0 + row) * SS + j0 + ch;
      float4 o0 = {h2f((unsigned short)(pv[p].x)) * cr,
                   h2f((unsigned short)(pv[p].x >> 16)) * cr,
                   h2f((unsigned short)(pv[p].y)) * cr,
                   h2f((unsigned short)(pv[p].y >> 16)) * cr};
      float4 o1 = {h2f((unsigned short)(pv[p].z)) * cr,
                   h2f((unsigned short)(pv[p].z >> 16)) * cr,
                   h2f((unsigned short)(pv[p].w)) * cr,
                   h2f((unsigned short)(pv[p].w >> 16)) * cr};
      *(float4*)&orow[0] = o0;
      *(float4*)&orow[4] = o1;
    }
    __syncthreads();
// MFMA: out(64x64) += P(64x64) @ V(64x64)
#pragma unroll
    for (int ks = 0; ks < 2; ++ks) {
      const int kb = ks * 32 + lq * 8;
      short8 a[2], bf[2];
#pragma unroll
      for (int mr = 0; mr < 2; ++mr)
        a[mr] = *(const short8*)&Ps[wr * 32 + mr * 16 + l16][kb];
#pragma unroll
      for (int nc = 0; nc < 2; ++nc)
        bf[nc] = *(const short8*)&Vts[wc * 32 + nc * 16 + l16][kb];
#pragma unroll
      for (int mr = 0; mr < 2; ++mr)
#pragma unroll
        for (int nc = 0; nc < 2; ++nc)
          acc[mr][nc] = __builtin_amdgcn_mfma_f32_16x16x32_f16(a[mr], bf[nc], acc[mr][nc], 0, 0, 0);
    }
  }

// epilogue: f16 write [b, s, h*64 + d]
#pragma unroll
  for (int mr = 0; mr < 2; ++mr)
#pragma unroll
    for (int nc = 0; nc < 2; ++nc)
#pragma unroll
      for (int jj = 0; jj < 4; ++jj) {
        const int i = i0 + wr * 32 + mr * 16 + lq * 4 + jj;
        const int d = wc * 32 + nc * 16 + l16;
        attn_out[((size_t)(b * SS + i)) * HID + h * HD + d] = f2h(acc[mr][nc][jj]);
      }
}

// ---------------------------------------------------------------------------
// Residual + LayerNorm
// ---------------------------------------------------------------------------
__global__ __launch_bounds__(256) void ln_kernel(const float* __restrict__ proj,
                                                 const float* __restrict__ query,
                                                 const float* __restrict__ gamma,
                                                 const float* __restrict__ beta,
                                                 float* __restrict__ out) {
  const int row = blockIdx.x;
  const int tid = threadIdx.x;

  float x[2];
  float sum = 0.f, sumsq = 0.f;
#pragma unroll
  for (int t = 0; t < 2; ++t) {
    const int c = tid + t * 256;
    float v = proj[(size_t)row * HID + c] + query[(size_t)row * HID + c];
    x[t] = v;
    sum += v;
    sumsq += v * v;
  }
#pragma unroll
  for (int off = 1; off < 64; off <<= 1) {
    sum += __shfl_xor(sum, off);
    sumsq += __shfl_xor(sumsq, off);
  }
  __shared__ float s1[4], s2[4];
  if ((tid & 63) == 0) {
    s1[tid >> 6] = sum;
    s2[tid >> 6] = sumsq;
  }
  __syncthreads();
  sum = s1[0] + s1[1] + s1[2] + s1[3];
  sumsq = s2[0] + s2[1] + s2[2] + s2[3];
  const float mu = sum * (1.f / HID);
  const float var = sumsq * (1.f / HID) - mu * mu;
  const float rstd = rsqrtf(var + EPSV);
#pragma unroll
  for (int t = 0; t < 2; ++t) {
    const int c = tid + t * 256;
    out[(size_t)row * HID + c] = (x[t] - mu) * rstd * gamma[c] + beta[c];
  }
}

// ---------------------------------------------------------------------------
extern "C" void kernel_launch(void* const* d_in, const int* in_sizes, int n_in,
                              void* d_out, int out_size, void* d_ws, size_t ws_size,
                              hipStream_t stream) {
  const float* query = (const float*)d_in[0];
  const float* key = (const float*)d_in[1];
  const float* value = (const float*)d_in[2];
  const int* mask = (const int*)d_in[3];
  const float* Wq = (const float*)d_in[4];
  const float* bq = (const float*)d_in[5];
  const float* Wk = (const float*)d_in[6];
  const float* bk = (const float*)d_in[7];
  const float* Wv = (const float*)d_in[8];
  const float* bv = (const float*)d_in[9];
  const float* Wo = (const float*)d_in[10];
  const float* bo = (const float*)d_in[11];
  const float* temp = (const float*)d_in[12];
  const float* gamma = (const float*)d_in[13];
  const float* beta = (const float*)d_in[14];

  float* out_final = (float*)d_out;                     // (B,S,HID)
  float* attn = (float*)d_out + (size_t)BB * SS * HID;  // (B,H,S,S)

  // workspace layout (36.5 MB total)
  unsigned short* Qh = (unsigned short*)d_ws;    // u16fx [bh][s][d]  8MB
  unsigned short* Kh = Qh + QKV_ELEMS;           // u16fx [bh][s][d]  8MB
  unsigned short* Vt = Kh + QKV_ELEMS;           // f16 [bh][d][s]    8MB
  unsigned short* aout = Vt + QKV_ELEMS;         // f16 [b*s][512]    8MB
  float* stats = (float*)(aout + QKV_ELEMS);     // 2 * TOTROWS       0.5MB
  float* msnap = stats + 2 * TOTROWS;            // NJT * TOTROWS     4MB
  float* proj = (float*)d_ws;                    // f32, aliases Qh+Kh (16MB)

  const dim3 blk(256);
  const dim3 ggrid(HID / 128, NROWS / 128);  // 4 x 64

  gemm_f16<3, false><<<ggrid, blk, 0, stream>>>(query, Wq, bq, Qh);
  gemm_f16<3, false><<<ggrid, blk, 0, stream>>>(key, Wk, bk, Kh);
  gemm_f16<2, false><<<ggrid, blk, 0, stream>>>(value, Wv, bv, Vt);

  const dim3 sgrid(SS / 64, BB * NH);  // 32 x 32
  scores_kernel<<<sgrid, dim3(512), 0, stream>>>(Qh, Kh, mask, temp, attn, stats, msnap);
  attn_pv_norm_kernel<<<sgrid, blk, 0, stream>>>(Vt, stats, msnap, attn, aout);

  gemm_f16<0, true><<<ggrid, blk, 0, stream>>>(aout, Wo, bo, proj);
  ln_kernel<<<NROWS, blk, 0, stream>>>(proj, query, gamma, beta, out_final);
}